// Round 14
// baseline (231.189 us; speedup 1.0000x reference)
//
#include <hip/hip_runtime.h>
#include <hip/hip_bf16.h>

// B=128, C=20000, F=64, K=32.
// Outputs flat-concat: fa [B*C*64] | ca [B*C] | mean [B] | pred [B], all f32.
//
// Measured ledger (r1-r13):
//   fused fa_ca NQ=4 NT = ~150 µs (r10 best); NQ=8 same; regular stores +9;
//   lvl>0 hist privatization = noise (r13). Plateau 186-188 over r10-r13.
//   topk v4 = ~36 µs (latency-bound, 128 blocks, ~6 full-row passes).
//   THIS ROUND: fa_ca as grid-stride address-linear streamer (compact sliding
//   write window, mimics fill kernel's 6.8 TB/s shape). One variable.

#define EPS_DENOM 1e-10f

typedef float floatx4 __attribute__((ext_vector_type(4)));

// ---------------------------------------------------------------------------
// Kernel 1: fused fa+ca, grid-stride over (b, 64-case strip) chunks in LINEAR
// fa-address order. Concurrent write front = gridDim * 16KB sliding window.
// Inner arithmetic identical to r3/r10 (top-k boundary safe).
// ---------------------------------------------------------------------------
__global__ __launch_bounds__(256) void fa_ca_stream_kernel(
    const float* __restrict__ q,
    const float* __restrict__ cases,
    const float* __restrict__ w_fa,
    const float* __restrict__ b_fa,
    const float* __restrict__ w_ca,
    const float* __restrict__ b_ca,
    float* __restrict__ fa_out,
    float* __restrict__ ca_out,
    int B, int C, int CB /* chunks per row = ceil(C/64) */)
{
    const int g  = threadIdx.x & 15;   // feature group (features g*4 .. g*4+3)
    const int p  = threadIdx.x >> 4;   // case slot within chunk (0..15)
    const int f4 = g * 4;

    const float4 wf = *reinterpret_cast<const float4*>(w_fa + f4);
    const float4 bf = *reinterpret_cast<const float4*>(b_fa + f4);
    const float4 wc = *reinterpret_cast<const float4*>(w_ca + f4);
    const float  bca = b_ca[0];

    const int nchunks = B * CB;

    for (int chunk = blockIdx.x; chunk < nchunks; chunk += gridDim.x) {
        const int b  = chunk / CB;               // block-uniform (SALU)
        const int c0 = (chunk - b * CB) * 64 + p;

        const float4 qv = *reinterpret_cast<const float4*>(q + (size_t)b * 64 + f4);

        #pragma unroll
        for (int j = 0; j < 4; ++j) {
            const int c = c0 + j * 16;
            if (c >= C) break;  // uniform within each 16-lane case group

            const float4 cv = *reinterpret_cast<const float4*>(cases + (size_t)c * 64 + f4);
            float d0 = qv.x - cv.x, d1 = qv.y - cv.y;
            float d2 = qv.z - cv.z, d3 = qv.w - cv.w;
            float s0 = 1.0f / (1.0f + __expf(fmaf(d0 * d0, wf.x, -bf.x)));
            float s1 = 1.0f / (1.0f + __expf(fmaf(d1 * d1, wf.y, -bf.y)));
            float s2 = 1.0f / (1.0f + __expf(fmaf(d2 * d2, wf.z, -bf.z)));
            float s3 = 1.0f / (1.0f + __expf(fmaf(d3 * d3, wf.w, -bf.w)));

            floatx4 sv = { s0, s1, s2, s3 };
            __builtin_nontemporal_store(
                sv, reinterpret_cast<floatx4*>(fa_out + ((size_t)b * C + c) * 64 + f4));

            float dot = s0 * wc.x + s1 * wc.y + s2 * wc.z + s3 * wc.w;
            dot += __shfl_xor(dot, 1, 64);
            dot += __shfl_xor(dot, 2, 64);
            dot += __shfl_xor(dot, 4, 64);
            dot += __shfl_xor(dot, 8, 64);

            if (g == 0) {
                float cav = 1.0f / (1.0f + __expf(-(dot + bca)));
                ca_out[(size_t)b * C + c] = cav;  // raw; topk rewrites in place
            }
        }
    }
}

// ---------------------------------------------------------------------------
// Kernel 2: LDS-resident top-K, v4 (r10-exact).
// ---------------------------------------------------------------------------
#define TPB3     1024
#define NWAVE    (TPB3 / 64)
#define NBINS    1024
#define NPRIV    8
#define CAND_CAP 2048
#define ROWCAP   20000   // requires C <= ROWCAP

__global__ __launch_bounds__(TPB3) void topk_kernel4(
    float* __restrict__ ca,
    const float* __restrict__ labels,
    float* __restrict__ out_mean,
    float* __restrict__ out_pred,
    int C, const int* __restrict__ kp)
{
    __shared__ float    row_lds[ROWCAP];
    __shared__ unsigned histf[NBINS * NPRIV];  // privatized lvl-0 hist
    __shared__ unsigned hist2[NBINS];
    __shared__ unsigned sc[NBINS];             // suffix sums
    __shared__ unsigned cand_key[CAND_CAP];
    __shared__ int      cand_idx[CAND_CAP];
    __shared__ float    s_wa[NWAVE], s_wb[NWAVE];
    __shared__ float    s_resA;
    __shared__ int      s_cand_cnt;
    __shared__ unsigned s_bsel;
    __shared__ int      s_thr_hi, s_thr_lo;

    const int b    = blockIdx.x;
    const int t    = threadIdx.x;
    const int w    = t >> 6;
    const int lane = t & 63;
    float* rowg = ca + (size_t)b * C;

    int K = *kp;
    if (K < 1) K = 1;
    if (K > 256) K = 256;

    #pragma unroll
    for (int r = 0; r < NPRIV; ++r) histf[r * NBINS + t] = 0;
    __syncthreads();

    // P1: global->LDS load + fused level-0 histogram (bin = key>>21)
    const int priv = w & (NPRIV - 1);
    for (int i = t; i < C; i += TPB3) {
        float v = rowg[i];
        row_lds[i] = v;
        atomicAdd(&histf[(__float_as_uint(v) >> 21) * NPRIV + priv], 1u);
    }
    __syncthreads();

    {
        unsigned hm = 0;
        #pragma unroll
        for (int r = 0; r < NPRIV; ++r) hm += histf[t * NPRIV + r];
        hist2[t] = hm;
    }
    __syncthreads();

    unsigned prefix = 0, pmask = 0;
    int R = K;
    int cnt_bin = 0;
    const int shifts[3] = {21, 11, 1};

    for (int lvl = 0; lvl < 3; ++lvl) {
        const int shift = shifts[lvl];
        if (lvl > 0) {
            hist2[t] = 0;
            __syncthreads();
            for (int i = t; i < C; i += TPB3) {
                unsigned key = __float_as_uint(row_lds[i]);
                if ((key & pmask) == prefix)
                    atomicAdd(&hist2[(key >> shift) & (NBINS - 1u)], 1u);
            }
            __syncthreads();
        }
        // suffix scan by wave 0 only
        if (w == 0) {
            unsigned v16[16], locsuf[16];
            #pragma unroll
            for (int m = 0; m < 16; ++m) v16[m] = hist2[lane * 16 + m];
            unsigned acc = 0;
            #pragma unroll
            for (int m = 15; m >= 0; --m) { acc += v16[m]; locsuf[m] = acc; }
            const unsigned lanetot = acc;
            unsigned suf = lanetot;
            #pragma unroll
            for (int off = 1; off < 64; off <<= 1) {
                unsigned o = __shfl_down(suf, (unsigned)off, 64);
                if (lane + off < 64) suf += o;
            }
            const unsigned baseh = suf - lanetot;
            #pragma unroll
            for (int m = 0; m < 16; ++m) sc[lane * 16 + m] = baseh + locsuf[m];
        }
        __syncthreads();
        {
            unsigned inc    = sc[t];
            unsigned strict = (t < NBINS - 1) ? sc[t + 1] : 0u;
            if ((int)strict < R && R <= (int)inc) s_bsel = (unsigned)t;
        }
        __syncthreads();
        const unsigned bsel       = s_bsel;
        const unsigned strict_sel = (bsel < NBINS - 1) ? sc[bsel + 1] : 0u;
        cnt_bin = (int)(sc[bsel] - strict_sel);
        R      -= (int)strict_sel;
        prefix |= bsel << shift;
        pmask  |= (NBINS - 1u) << shift;
        __syncthreads();
        if (cnt_bin <= CAND_CAP) break;
    }

    const bool tieflood = (cnt_bin > CAND_CAP);
    float my_selsum = 0.0f;
    bool sel0 = false, sel1 = false;
    unsigned k0 = 0, k1 = 0;
    int i0 = 0x7FFFFFFF, i1 = 0x7FFFFFFF;

    if (!tieflood) {
        if (t == 0) s_cand_cnt = 0;
        __syncthreads();
        // compact candidates (wave-aggregated: ONE atomic per wave-batch)
        for (int ib = 0; ib < C; ib += TPB3) {
            const int i = ib + t;
            bool is_cand = false;
            unsigned key = 0;
            if (i < C) {
                float v = row_lds[i];
                key = __float_as_uint(v);
                unsigned mk = key & pmask;
                if (mk > prefix)        my_selsum += v;
                else if (mk == prefix)  is_cand = true;
            }
            unsigned long long m = __ballot(is_cand);
            if (m) {
                const int ldr = (int)(__ffsll((unsigned long long)m) - 1);
                int base = 0;
                if (lane == ldr) base = atomicAdd(&s_cand_cnt, __popcll(m));
                base = __shfl(base, ldr, 64);
                if (is_cand) {
                    int pos = base + (int)__popcll(m & ((1ull << lane) - 1ull));
                    if (pos < CAND_CAP) { cand_key[pos] = key; cand_idx[pos] = i; }
                }
            }
        }
        __syncthreads();
        const int n_c = (s_cand_cnt < CAND_CAP) ? s_cand_cnt : CAND_CAP;
        if (t < n_c)        { k0 = cand_key[t];        i0 = cand_idx[t]; }
        if (t + TPB3 < n_c) { k1 = cand_key[t + TPB3]; i1 = cand_idx[t + TPB3]; }
        int r0 = 0, r1 = 0;
        for (int j = 0; j < n_c; ++j) {   // broadcast reads: conflict-free
            unsigned kj = cand_key[j];
            int      ij = cand_idx[j];
            r0 += (kj > k0 || (kj == k0 && ij < i0)) ? 1 : 0;
            r1 += (kj > k1 || (kj == k1 && ij < i1)) ? 1 : 0;
        }
        sel0 = (t < n_c) && (r0 < R);
        sel1 = (t + TPB3 < n_c) && (r1 < R);
        if (sel0) my_selsum += __uint_as_float(k0);
        if (sel1) my_selsum += __uint_as_float(k1);
    } else {
        // all candidates equal in bits [30:1]; pick by (bit0 desc, idx asc)
        if (t == 0) {
            int n1 = 0;
            for (int i = 0; i < C; ++i) {
                unsigned key = __float_as_uint(row_lds[i]);
                if ((key & pmask) == prefix && (key & 1u)) n1++;
            }
            int thr_hi = -1, thr_lo = -1;
            if (R <= n1) {
                int cnt = 0;
                for (int i = 0; i < C; ++i) {
                    unsigned key = __float_as_uint(row_lds[i]);
                    if ((key & pmask) == prefix && (key & 1u))
                        if (++cnt == R) { thr_hi = i; break; }
                }
            } else {
                thr_hi = C;
                int need = R - n1, cnt = 0;
                for (int i = 0; i < C; ++i) {
                    unsigned key = __float_as_uint(row_lds[i]);
                    if ((key & pmask) == prefix && !(key & 1u))
                        if (++cnt == need) { thr_lo = i; break; }
                }
            }
            s_thr_hi = thr_hi; s_thr_lo = thr_lo;
        }
        __syncthreads();
        const int thr_hi = s_thr_hi, thr_lo = s_thr_lo;
        for (int i = t; i < C; i += TPB3) {
            float v = row_lds[i];
            unsigned key = __float_as_uint(v);
            unsigned mk  = key & pmask;
            bool sel = (mk > prefix) ||
                       (mk == prefix && ((key & 1u) ? (i <= thr_hi) : (i <= thr_lo)));
            if (sel) my_selsum += v;
        }
    }

    // reduce selected-sum -> denom (shfl butterfly + wave-0 finish)
    {
        float a = my_selsum;
        #pragma unroll
        for (int off = 1; off < 64; off <<= 1) a += __shfl_xor(a, off, 64);
        if (lane == 0) s_wa[w] = a;
        __syncthreads();
        if (w == 0) {
            float x = (lane < NWAVE) ? s_wa[lane] : 0.0f;
            #pragma unroll
            for (int off = 1; off < NWAVE; off <<= 1) x += __shfl_xor(x, off, 64);
            if (lane == 0) s_resA = x;
        }
        __syncthreads();
    }
    const float denom = s_resA + EPS_DENOM;
    __syncthreads();

    // write pass + label sums
    float lsum = 0.0f, psum = 0.0f;
    const int thr_hi2 = tieflood ? s_thr_hi : 0;
    const int thr_lo2 = tieflood ? s_thr_lo : 0;
    for (int i = t; i < C; i += TPB3) {
        float v = row_lds[i];
        unsigned key = __float_as_uint(v);
        unsigned mk  = key & pmask;
        bool sel = (mk > prefix);
        if (tieflood && !sel && mk == prefix)
            sel = (key & 1u) ? (i <= thr_hi2) : (i <= thr_lo2);
        float outv = 0.0f;
        if (sel) {
            outv = v / denom;
            float lab = labels[i];
            lsum += lab;
            psum += outv * lab;
        }
        rowg[i] = outv;
    }
    __syncthreads();
    if (!tieflood) {   // selected candidates (write pass wrote 0 there)
        if (sel0) {
            float ov = __uint_as_float(k0) / denom;
            rowg[i0] = ov;
            float lab = labels[i0];
            lsum += lab; psum += ov * lab;
        }
        if (sel1) {
            float ov = __uint_as_float(k1) / denom;
            rowg[i1] = ov;
            float lab = labels[i1];
            lsum += lab; psum += ov * lab;
        }
    }
    {
        float a = lsum, bb = psum;
        #pragma unroll
        for (int off = 1; off < 64; off <<= 1) {
            a  += __shfl_xor(a,  off, 64);
            bb += __shfl_xor(bb, off, 64);
        }
        if (lane == 0) { s_wa[w] = a; s_wb[w] = bb; }
        __syncthreads();
        if (w == 0) {
            float x = (lane < NWAVE) ? s_wa[lane] : 0.0f;
            float y = (lane < NWAVE) ? s_wb[lane] : 0.0f;
            #pragma unroll
            for (int off = 1; off < NWAVE; off <<= 1) {
                x += __shfl_xor(x, off, 64);
                y += __shfl_xor(y, off, 64);
            }
            if (lane == 0) {
                out_mean[b] = x / (float)K;
                out_pred[b] = y;
            }
        }
    }
}

extern "C" void kernel_launch(void* const* d_in, const int* in_sizes, int n_in,
                              void* d_out, int out_size, void* d_ws, size_t ws_size,
                              hipStream_t stream) {
    const float* q      = (const float*)d_in[0];
    const float* cases  = (const float*)d_in[1];
    const float* labels = (const float*)d_in[2];
    const float* w_fa   = (const float*)d_in[3];
    const float* b_fa   = (const float*)d_in[4];
    const float* w_ca   = (const float*)d_in[5];
    const float* b_ca   = (const float*)d_in[6];
    const int*   kp     = (const int*)d_in[7];

    const int F = in_sizes[3];          // 64
    const int B = in_sizes[0] / F;      // 128
    const int C = in_sizes[1] / F;      // 20000

    float* out      = (float*)d_out;
    const size_t FA = (size_t)B * C * F;
    float* fa_out   = out;
    float* ca_out   = out + FA;
    float* out_mean = ca_out + (size_t)B * C;
    float* out_pred = out_mean + B;

    const int CB = (C + 63) / 64;       // 313
    const int grid1 = 2048;             // compact sliding write window
    fa_ca_stream_kernel<<<grid1, 256, 0, stream>>>(
        q, cases, w_fa, b_fa, w_ca, b_ca, fa_out, ca_out, B, C, CB);
    topk_kernel4<<<B, TPB3, 0, stream>>>(ca_out, labels, out_mean, out_pred,
                                         C, kp);
}

// Round 15
// 184.461 us; speedup vs baseline: 1.2533x; 1.2533x over previous
//
#include <hip/hip_runtime.h>
#include <hip/hip_bf16.h>

// B=128, C=20000, F=64, K=32.
// Outputs flat-concat: fa [B*C*64] | ca [B*C] | mean [B] | pred [B], all f32.
//
// Measured ledger (r1-r14):
//   fused fa_ca NQ=4 NT (r10 shape) = ~150 µs — STRUCTURAL FLOOR. Shape probes
//   all <= 0: b-loop(r5), NQ=8(r11), regular stores(r12, -9), hist-priv(r13),
//   grid-stride(r14, -45). Do not touch again.
//   topk: 198.6 (global) -> 92 (LDS) -> 69 (v3) -> ~36 (v4).
//   THIS ROUND: topk v6 = v4 with (a) row-zeroing fused into load pass,
//   (b) O(32) scatter finale (nonzeros = gt-set<32 + selected ties) instead
//   of a 4th full row pass. fa_ca = r10-exact.

#define EPS_DENOM 1e-10f

typedef float floatx4 __attribute__((ext_vector_type(4)));

// ---------------------------------------------------------------------------
// Kernel 1: fused feature_activations + case activations (r10-exact).
// ---------------------------------------------------------------------------
#define NQ 4

__global__ __launch_bounds__(256) void fa_ca_kernel(
    const float* __restrict__ q,
    const float* __restrict__ cases,
    const float* __restrict__ w_fa,
    const float* __restrict__ b_fa,
    const float* __restrict__ w_ca,
    const float* __restrict__ b_ca,
    float* __restrict__ fa_out,
    float* __restrict__ ca_out,
    int B, int C)
{
    const int g  = threadIdx.x & 15;   // feature group (features g*4 .. g*4+3)
    const int p  = threadIdx.x >> 4;   // case slot within block (0..15)
    const int b0 = blockIdx.y * NQ;
    const int c0 = blockIdx.x * 64 + p;
    const int f4 = g * 4;

    const float4 wf = *reinterpret_cast<const float4*>(w_fa + f4);
    const float4 bf = *reinterpret_cast<const float4*>(b_fa + f4);
    const float4 wc = *reinterpret_cast<const float4*>(w_ca + f4);
    const float  bca = b_ca[0];

    float4 qv[NQ];
    #pragma unroll
    for (int i = 0; i < NQ; ++i) {
        int bq = b0 + i;
        if (bq > B - 1) bq = B - 1;   // clamp load; writes guarded below
        qv[i] = *reinterpret_cast<const float4*>(q + (size_t)bq * 64 + f4);
    }

    #pragma unroll
    for (int j = 0; j < 4; ++j) {
        const int c = c0 + j * 16;
        if (c >= C) break;  // uniform within each 16-lane case group

        const float4 cv = *reinterpret_cast<const float4*>(cases + (size_t)c * 64 + f4);

        #pragma unroll
        for (int i = 0; i < NQ; ++i) {
            const int b = b0 + i;
            if (b >= B) break;  // block-uniform

            float d0 = qv[i].x - cv.x, d1 = qv[i].y - cv.y;
            float d2 = qv[i].z - cv.z, d3 = qv[i].w - cv.w;
            float s0 = 1.0f / (1.0f + __expf(fmaf(d0 * d0, wf.x, -bf.x)));
            float s1 = 1.0f / (1.0f + __expf(fmaf(d1 * d1, wf.y, -bf.y)));
            float s2 = 1.0f / (1.0f + __expf(fmaf(d2 * d2, wf.z, -bf.z)));
            float s3 = 1.0f / (1.0f + __expf(fmaf(d3 * d3, wf.w, -bf.w)));

            floatx4 sv = { s0, s1, s2, s3 };
            __builtin_nontemporal_store(
                sv, reinterpret_cast<floatx4*>(fa_out + ((size_t)b * C + c) * 64 + f4));

            float dot = s0 * wc.x + s1 * wc.y + s2 * wc.z + s3 * wc.w;
            dot += __shfl_xor(dot, 1, 64);
            dot += __shfl_xor(dot, 2, 64);
            dot += __shfl_xor(dot, 4, 64);
            dot += __shfl_xor(dot, 8, 64);

            if (g == 0) {
                float cav = 1.0f / (1.0f + __expf(-(dot + bca)));
                ca_out[(size_t)b * C + c] = cav;  // raw; topk rewrites in place
            }
        }
    }
}

// ---------------------------------------------------------------------------
// Kernel 2: LDS-resident top-K, v6.
//  vs v4: (a) rowg zeroed during the load pass; (b) gt-set indices (<K)
//  collected during compaction; (c) finale scatters only the K nonzero
//  outputs (no 4th full row pass). Tieflood fallback keeps a row pass but
//  writes only selected entries (row already zeroed).
// ---------------------------------------------------------------------------
#define TPB3     1024
#define NWAVE    (TPB3 / 64)
#define NBINS    1024
#define NPRIV    8
#define CAND_CAP 2048
#define GT_CAP   256
#define ROWCAP   20000   // requires C <= ROWCAP

__global__ __launch_bounds__(TPB3) void topk_kernel6(
    float* __restrict__ ca,
    const float* __restrict__ labels,
    float* __restrict__ out_mean,
    float* __restrict__ out_pred,
    int C, const int* __restrict__ kp)
{
    __shared__ float    row_lds[ROWCAP];
    __shared__ unsigned histf[NBINS * NPRIV];  // privatized lvl-0 hist
    __shared__ unsigned hist2[NBINS];
    __shared__ unsigned sc[NBINS];             // suffix sums
    __shared__ unsigned cand_key[CAND_CAP];
    __shared__ int      cand_idx[CAND_CAP];
    __shared__ float    gt_val[GT_CAP];
    __shared__ int      gt_idx[GT_CAP];
    __shared__ float    s_wa[NWAVE], s_wb[NWAVE];
    __shared__ float    s_resA;
    __shared__ int      s_cand_cnt, s_gt_cnt;
    __shared__ unsigned s_bsel;
    __shared__ int      s_thr_hi, s_thr_lo;

    const int b    = blockIdx.x;
    const int t    = threadIdx.x;
    const int w    = t >> 6;
    const int lane = t & 63;
    float* rowg = ca + (size_t)b * C;

    int K = *kp;
    if (K < 1) K = 1;
    if (K > 256) K = 256;

    #pragma unroll
    for (int r = 0; r < NPRIV; ++r) histf[r * NBINS + t] = 0;
    __syncthreads();

    // P1: load -> LDS, zero rowg (only K entries rewritten later), lvl-0 hist
    const int priv = w & (NPRIV - 1);
    for (int i = t; i < C; i += TPB3) {
        float v = rowg[i];
        row_lds[i] = v;
        rowg[i] = 0.0f;
        atomicAdd(&histf[(__float_as_uint(v) >> 21) * NPRIV + priv], 1u);
    }
    __syncthreads();

    {
        unsigned hm = 0;
        #pragma unroll
        for (int r = 0; r < NPRIV; ++r) hm += histf[t * NPRIV + r];
        hist2[t] = hm;
    }
    __syncthreads();

    unsigned prefix = 0, pmask = 0;
    int R = K;
    int cnt_bin = 0;
    const int shifts[3] = {21, 11, 1};

    for (int lvl = 0; lvl < 3; ++lvl) {
        const int shift = shifts[lvl];
        if (lvl > 0) {
            hist2[t] = 0;
            __syncthreads();
            for (int i = t; i < C; i += TPB3) {
                unsigned key = __float_as_uint(row_lds[i]);
                if ((key & pmask) == prefix)
                    atomicAdd(&hist2[(key >> shift) & (NBINS - 1u)], 1u);
            }
            __syncthreads();
        }
        // suffix scan by wave 0 only
        if (w == 0) {
            unsigned v16[16], locsuf[16];
            #pragma unroll
            for (int m = 0; m < 16; ++m) v16[m] = hist2[lane * 16 + m];
            unsigned acc = 0;
            #pragma unroll
            for (int m = 15; m >= 0; --m) { acc += v16[m]; locsuf[m] = acc; }
            const unsigned lanetot = acc;
            unsigned suf = lanetot;
            #pragma unroll
            for (int off = 1; off < 64; off <<= 1) {
                unsigned o = __shfl_down(suf, (unsigned)off, 64);
                if (lane + off < 64) suf += o;
            }
            const unsigned baseh = suf - lanetot;
            #pragma unroll
            for (int m = 0; m < 16; ++m) sc[lane * 16 + m] = baseh + locsuf[m];
        }
        __syncthreads();
        {
            unsigned inc    = sc[t];
            unsigned strict = (t < NBINS - 1) ? sc[t + 1] : 0u;
            if ((int)strict < R && R <= (int)inc) s_bsel = (unsigned)t;
        }
        __syncthreads();
        const unsigned bsel       = s_bsel;
        const unsigned strict_sel = (bsel < NBINS - 1) ? sc[bsel + 1] : 0u;
        cnt_bin = (int)(sc[bsel] - strict_sel);
        R      -= (int)strict_sel;
        prefix |= bsel << shift;
        pmask  |= (NBINS - 1u) << shift;
        __syncthreads();
        if (cnt_bin <= CAND_CAP) break;
    }

    const bool tieflood = (cnt_bin > CAND_CAP);
    float my_selsum = 0.0f;
    bool sel0 = false, sel1 = false;
    unsigned k0 = 0, k1 = 0;
    int i0 = 0x7FFFFFFF, i1 = 0x7FFFFFFF;

    if (!tieflood) {
        if (t == 0) { s_cand_cnt = 0; s_gt_cnt = 0; }
        __syncthreads();
        // P-compact: gt-set (<K) collected; candidates wave-aggregated
        for (int ib = 0; ib < C; ib += TPB3) {
            const int i = ib + t;
            bool is_cand = false;
            unsigned key = 0;
            if (i < C) {
                float v = row_lds[i];
                key = __float_as_uint(v);
                unsigned mk = key & pmask;
                if (mk > prefix) {
                    my_selsum += v;
                    int gs = atomicAdd(&s_gt_cnt, 1);
                    if (gs < GT_CAP) { gt_val[gs] = v; gt_idx[gs] = i; }
                } else if (mk == prefix) {
                    is_cand = true;
                }
            }
            unsigned long long m = __ballot(is_cand);
            if (m) {
                const int ldr = (int)(__ffsll((unsigned long long)m) - 1);
                int base = 0;
                if (lane == ldr) base = atomicAdd(&s_cand_cnt, __popcll(m));
                base = __shfl(base, ldr, 64);
                if (is_cand) {
                    int pos = base + (int)__popcll(m & ((1ull << lane) - 1ull));
                    if (pos < CAND_CAP) { cand_key[pos] = key; cand_idx[pos] = i; }
                }
            }
        }
        __syncthreads();
        const int n_c = (s_cand_cnt < CAND_CAP) ? s_cand_cnt : CAND_CAP;
        if (t < n_c)        { k0 = cand_key[t];        i0 = cand_idx[t]; }
        if (t + TPB3 < n_c) { k1 = cand_key[t + TPB3]; i1 = cand_idx[t + TPB3]; }
        int r0 = 0, r1 = 0;
        for (int j = 0; j < n_c; ++j) {   // broadcast reads: conflict-free
            unsigned kj = cand_key[j];
            int      ij = cand_idx[j];
            r0 += (kj > k0 || (kj == k0 && ij < i0)) ? 1 : 0;
            r1 += (kj > k1 || (kj == k1 && ij < i1)) ? 1 : 0;
        }
        sel0 = (t < n_c) && (r0 < R);
        sel1 = (t + TPB3 < n_c) && (r1 < R);
        if (sel0) my_selsum += __uint_as_float(k0);
        if (sel1) my_selsum += __uint_as_float(k1);
    } else {
        // all candidates equal in bits [30:1]; pick by (bit0 desc, idx asc)
        if (t == 0) {
            int n1 = 0;
            for (int i = 0; i < C; ++i) {
                unsigned key = __float_as_uint(row_lds[i]);
                if ((key & pmask) == prefix && (key & 1u)) n1++;
            }
            int thr_hi = -1, thr_lo = -1;
            if (R <= n1) {
                int cnt = 0;
                for (int i = 0; i < C; ++i) {
                    unsigned key = __float_as_uint(row_lds[i]);
                    if ((key & pmask) == prefix && (key & 1u))
                        if (++cnt == R) { thr_hi = i; break; }
                }
            } else {
                thr_hi = C;
                int need = R - n1, cnt = 0;
                for (int i = 0; i < C; ++i) {
                    unsigned key = __float_as_uint(row_lds[i]);
                    if ((key & pmask) == prefix && !(key & 1u))
                        if (++cnt == need) { thr_lo = i; break; }
                }
            }
            s_thr_hi = thr_hi; s_thr_lo = thr_lo;
        }
        __syncthreads();
        const int thr_hi = s_thr_hi, thr_lo = s_thr_lo;
        for (int i = t; i < C; i += TPB3) {
            float v = row_lds[i];
            unsigned key = __float_as_uint(v);
            unsigned mk  = key & pmask;
            bool sel = (mk > prefix) ||
                       (mk == prefix && ((key & 1u) ? (i <= thr_hi) : (i <= thr_lo)));
            if (sel) my_selsum += v;
        }
    }

    // reduce selected-sum -> denom (shfl butterfly + wave-0 finish)
    {
        float a = my_selsum;
        #pragma unroll
        for (int off = 1; off < 64; off <<= 1) a += __shfl_xor(a, off, 64);
        if (lane == 0) s_wa[w] = a;
        __syncthreads();
        if (w == 0) {
            float x = (lane < NWAVE) ? s_wa[lane] : 0.0f;
            #pragma unroll
            for (int off = 1; off < NWAVE; off <<= 1) x += __shfl_xor(x, off, 64);
            if (lane == 0) s_resA = x;
        }
        __syncthreads();
    }
    const float denom = s_resA + EPS_DENOM;

    // finale: scatter the K nonzero outputs + label sums
    float lsum = 0.0f, psum = 0.0f;
    if (!tieflood) {
        if (sel0) {
            float ov = __uint_as_float(k0) / denom;
            rowg[i0] = ov;
            float lab = labels[i0];
            lsum += lab; psum += ov * lab;
        }
        if (sel1) {
            float ov = __uint_as_float(k1) / denom;
            rowg[i1] = ov;
            float lab = labels[i1];
            lsum += lab; psum += ov * lab;
        }
        const int n_gt = (s_gt_cnt < GT_CAP) ? s_gt_cnt : GT_CAP;
        if (t < n_gt) {
            float v  = gt_val[t];
            float ov = v / denom;
            rowg[gt_idx[t]] = ov;
            float lab = labels[gt_idx[t]];
            lsum += lab; psum += ov * lab;
        }
    } else {
        const int thr_hi2 = s_thr_hi, thr_lo2 = s_thr_lo;
        for (int i = t; i < C; i += TPB3) {
            float v = row_lds[i];
            unsigned key = __float_as_uint(v);
            unsigned mk  = key & pmask;
            bool sel = (mk > prefix) ||
                       (mk == prefix && ((key & 1u) ? (i <= thr_hi2) : (i <= thr_lo2)));
            if (sel) {
                float ov = v / denom;
                rowg[i] = ov;           // row pre-zeroed in P1
                float lab = labels[i];
                lsum += lab; psum += ov * lab;
            }
        }
    }
    {
        float a = lsum, bb = psum;
        #pragma unroll
        for (int off = 1; off < 64; off <<= 1) {
            a  += __shfl_xor(a,  off, 64);
            bb += __shfl_xor(bb, off, 64);
        }
        if (lane == 0) { s_wa[w] = a; s_wb[w] = bb; }
        __syncthreads();
        if (w == 0) {
            float x = (lane < NWAVE) ? s_wa[lane] : 0.0f;
            float y = (lane < NWAVE) ? s_wb[lane] : 0.0f;
            #pragma unroll
            for (int off = 1; off < NWAVE; off <<= 1) {
                x += __shfl_xor(x, off, 64);
                y += __shfl_xor(y, off, 64);
            }
            if (lane == 0) {
                out_mean[b] = x / (float)K;
                out_pred[b] = y;
            }
        }
    }
}

extern "C" void kernel_launch(void* const* d_in, const int* in_sizes, int n_in,
                              void* d_out, int out_size, void* d_ws, size_t ws_size,
                              hipStream_t stream) {
    const float* q      = (const float*)d_in[0];
    const float* cases  = (const float*)d_in[1];
    const float* labels = (const float*)d_in[2];
    const float* w_fa   = (const float*)d_in[3];
    const float* b_fa   = (const float*)d_in[4];
    const float* w_ca   = (const float*)d_in[5];
    const float* b_ca   = (const float*)d_in[6];
    const int*   kp     = (const int*)d_in[7];

    const int F = in_sizes[3];          // 64
    const int B = in_sizes[0] / F;      // 128
    const int C = in_sizes[1] / F;      // 20000

    float* out      = (float*)d_out;
    const size_t FA = (size_t)B * C * F;
    float* fa_out   = out;
    float* ca_out   = out + FA;
    float* out_mean = ca_out + (size_t)B * C;
    float* out_pred = out_mean + B;

    dim3 g1((C + 63) / 64, (B + NQ - 1) / NQ);
    fa_ca_kernel<<<g1, 256, 0, stream>>>(q, cases, w_fa, b_fa, w_ca, b_ca,
                                         fa_out, ca_out, B, C);
    topk_kernel6<<<B, TPB3, 0, stream>>>(ca_out, labels, out_mean, out_pred,
                                         C, kp);
}